// Round 3
// baseline (1957.688 us; speedup 1.0000x reference)
//
#include <hip/hip_runtime.h>
#include <hip/hip_bf16.h>

#define N_NODES 50000
#define N_ENV   1000000
#define N_EDGES 200000

// tanh(x) = (e^{2x}-1)/(e^{2x}+1); clamp so exp never overflows
__device__ __forceinline__ float fast_tanh(float x){
  float xc = fminf(fmaxf(x, -10.f), 10.f);
  float t  = __expf(2.f * xc);
  return __fdividef(t - 1.f, t + 1.f);
}

__global__ void k_zero_i(int* __restrict__ p, int n){
  int i = blockIdx.x * blockDim.x + threadIdx.x;
  int stride = gridDim.x * blockDim.x;
  for (; i < n; i += stride) p[i] = 0;
}

// ---- CSR build: histogram by dst node ----
__global__ __launch_bounds__(256) void k_hist(
    const int* __restrict__ env_index, int* __restrict__ counts)
{
  int e = blockIdx.x * 256 + threadIdx.x;
  if (e >= N_ENV) return;
  atomicAdd(counts + env_index[N_ENV + e], 1);
}

// ---- single-wave exclusive scan over 50K counts (8 elems/lane/iter) ----
__global__ __launch_bounds__(64) void k_scan(
    const int* __restrict__ counts, int* __restrict__ offsets,
    int* __restrict__ cursor)
{
  int lane = threadIdx.x;
  int carry = 0;
  for (int base = 0; base < N_NODES; base += 512){
    int i0 = base + lane * 8;
    int c[8];
    #pragma unroll
    for (int j = 0; j < 8; j++){ int i = i0 + j; c[j] = (i < N_NODES) ? counts[i] : 0; }
    int local = 0;
    #pragma unroll
    for (int j = 0; j < 8; j++) local += c[j];
    int incl = local;
    #pragma unroll
    for (int off = 1; off < 64; off <<= 1){
      int t = __shfl_up(incl, off);
      if (lane >= off) incl += t;
    }
    int run = carry + incl - local;   // exclusive prefix for this lane's first elem
    #pragma unroll
    for (int j = 0; j < 8; j++){
      int i = i0 + j;
      if (i < N_NODES){ offsets[i] = run; cursor[i] = run; }
      run += c[j];
    }
    carry += __shfl(incl, 63);
  }
}

// ---- CSR build: scatter env ids into dst-grouped order ----
__global__ __launch_bounds__(256) void k_scatter(
    const int* __restrict__ env_index, int* __restrict__ cursor,
    int* __restrict__ order)
{
  int e = blockIdx.x * 256 + threadIdx.x;
  if (e >= N_ENV) return;
  int dst = env_index[N_ENV + e];
  int pos = atomicAdd(cursor + dst, 1);
  order[pos] = e;
}

// ---- MLP per env, writes h row with burst stores (full-line L2 merge) ----
__global__ __launch_bounds__(256) void k_mlp(
    const float* __restrict__ env_vec, const float* __restrict__ atom_attr,
    const int*  __restrict__ env_index,
    const float* __restrict__ W1, const float* __restrict__ B1,
    const float* __restrict__ W2, const float* __restrict__ B2,
    const float* __restrict__ W3, const float* __restrict__ B3,
    float* __restrict__ h_out)
{
  // Transposed weights in LDS: contiguous along the reduction dim so the
  // wave-uniform inner-loop reads merge into broadcast ds_read_b128.
  __shared__ float sW1[32*9];    // sW1[j*9+i]  = W1[i*32+j]
  __shared__ float sW2[64*32];   // sW2[j*32+i] = W2[i*64+j]
  __shared__ float sW3[64*64];   // sW3[j*64+i] = W3[i*64+j]
  __shared__ float sB1[32], sB2[64], sB3[64];
  for (int k = threadIdx.x; k < 32*9;  k += 256){ int j = k/9,  i = k%9;  sW1[k] = W1[i*32+j]; }
  for (int k = threadIdx.x; k < 64*32; k += 256){ int j = k>>5, i = k&31; sW2[k] = W2[i*64+j]; }
  for (int k = threadIdx.x; k < 64*64; k += 256){ int j = k>>6, i = k&63; sW3[k] = W3[i*64+j]; }
  if (threadIdx.x < 32) sB1[threadIdx.x] = B1[threadIdx.x];
  if (threadIdx.x < 64) sB2[threadIdx.x] = B2[threadIdx.x];
  if (threadIdx.x < 64) sB3[threadIdx.x] = B3[threadIdx.x];
  __syncthreads();

  int e = blockIdx.x * 256 + threadIdx.x;
  if (e >= N_ENV) return;

  float v0 = env_vec[3*e+0];
  float v1 = env_vec[3*e+1];
  float v2 = env_vec[3*e+2];
  float r = sqrtf(v0*v0 + v1*v1 + v2*v2);
  float invr = 1.f / r;
  float xx = (r - 6.f) * (-1.f/3.f);                 // (r-RC)/(RS-RC)
  float mid = invr * (xx*xx*xx*(10.f + xx*(-15.f + 6.f*xx)) + 1.f);
  float snorm = (r < 3.f) ? invr : ((r < 6.f) ? mid : 0.f);

  int src = env_index[e];
  int dst = env_index[N_ENV + e];

  float x[9];
  x[0] = snorm;
  float4 sa = *reinterpret_cast<const float4*>(atom_attr + src*4);
  float4 da = *reinterpret_cast<const float4*>(atom_attr + dst*4);
  x[1]=sa.x; x[2]=sa.y; x[3]=sa.z; x[4]=sa.w;
  x[5]=da.x; x[6]=da.y; x[7]=da.z; x[8]=da.w;

  float h1[32];
  #pragma unroll
  for (int j = 0; j < 32; j++){
    float acc = sB1[j];
    #pragma unroll
    for (int i = 0; i < 9; i++) acc += x[i] * sW1[j*9 + i];
    h1[j] = fast_tanh(acc);
  }

  float h2[64];
  #pragma unroll
  for (int j = 0; j < 64; j++){
    float acc = sB2[j];
    #pragma unroll
    for (int i = 0; i < 32; i++) acc += h1[i] * sW2[j*32 + i];
    h2[j] = fast_tanh(acc);
  }

  float* hrow = h_out + (size_t)e * 64;
  // Layer 3 in two 32-output chunks; each chunk's 8 float4 stores are issued
  // back-to-back so the lane's 128B line is fully covered before eviction.
  #pragma unroll
  for (int dc = 0; dc < 2; dc++){
    float o[32];
    #pragma unroll
    for (int dd = 0; dd < 32; dd++){
      int d = dc*32 + dd;
      float acc = sB3[d];
      #pragma unroll
      for (int i = 0; i < 64; i++) acc += h2[i] * sW3[d*64 + i];
      o[dd] = fast_tanh(acc) + h2[d];
    }
    #pragma unroll
    for (int q = 0; q < 8; q++)
      *reinterpret_cast<float4*>(hrow + dc*32 + q*4) =
          make_float4(o[q*4], o[q*4+1], o[q*4+2], o[q*4+3]);
  }
}

// ---- one WAVE per node: lane d owns h[e][d]; fused aggregate + self-outer ----
__global__ __launch_bounds__(256) void k_aggr_node(
    const float* __restrict__ h, const float* __restrict__ env_vec,
    const int* __restrict__ offsets, const int* __restrict__ counts,
    const int* __restrict__ order, float* __restrict__ node_out)
{
  int wid  = (blockIdx.x * 256 + threadIdx.x) >> 6;   // node id (wave-uniform)
  int lane = threadIdx.x & 63;
  if (wid >= N_NODES) return;
  int off = offsets[wid];
  int c   = counts[wid];

  float a0 = 0.f, a1 = 0.f, a2 = 0.f;
  int e = (c > 0) ? order[off] : 0;
  for (int k = 0; k < c; k++){
    // e is wave-uniform (same wid across the wave) — hoist to SGPR so the
    // env_vec broadcasts and order prefetch go down the scalar-mem pipe.
    int eu = __builtin_amdgcn_readfirstlane(e);
    int en = (k + 1 < c) ? order[off + k + 1] : eu;   // prefetch next env id
    float hv = h[(size_t)eu * 64 + lane];             // coalesced 256B wave read
    float v0 = env_vec[3*eu+0];                       // scalar broadcast loads
    float v1 = env_vec[3*eu+1];
    float v2 = env_vec[3*eu+2];
    a0 += hv * v0;
    a1 += hv * v1;
    a2 += hv * v2;
    e = en;
  }
  float inv = 1.f / fmaxf((float)c, 1.f);
  a0 *= inv; a1 *= inv; a2 *= inv;

  // desc[d][e2] = dot(aggr[d], aggr[e2]), e2 < 8 — fetch aggr[e2] via shuffle
  float o[8];
  #pragma unroll
  for (int e2 = 0; e2 < 8; e2++){
    float b0 = __shfl(a0, e2);
    float b1 = __shfl(a1, e2);
    float b2 = __shfl(a2, e2);
    o[e2] = a0*b0 + a1*b1 + a2*b2;
  }
  float* dst = node_out + (size_t)wid * 512 + lane * 8;
  *reinterpret_cast<float4*>(dst)     = make_float4(o[0], o[1], o[2], o[3]);
  *reinterpret_cast<float4*>(dst + 4) = make_float4(o[4], o[5], o[6], o[7]);
}

// 2 edges per 256-thread block; 128 threads per edge, one float4 (16B) per thread
__global__ __launch_bounds__(256) void k_edge(
    const float* __restrict__ node_out, const int* __restrict__ edge_index,
    float* __restrict__ edge_out)
{
  int t = threadIdx.x;
  int e = blockIdx.x * 2 + (t >> 7);
  int l = t & 127;
  int s  = edge_index[e];
  int dn = edge_index[N_EDGES + e];
  const float4* rs = reinterpret_cast<const float4*>(node_out + (size_t)s  * 512);
  const float4* rd = reinterpret_cast<const float4*>(node_out + (size_t)dn * 512);
  float4 a = rs[l];
  float4 b = rd[l];
  float4 o = make_float4(a.x + b.x, a.y + b.y, a.z + b.z, a.w + b.w);
  reinterpret_cast<float4*>(edge_out + (size_t)e * 512)[l] = o;
}

extern "C" void kernel_launch(void* const* d_in, const int* in_sizes, int n_in,
                              void* d_out, int out_size, void* d_ws, size_t ws_size,
                              hipStream_t stream) {
  const float* env_vec    = (const float*)d_in[0];
  const float* atom_attr  = (const float*)d_in[1];
  const int*   env_index  = (const int*)  d_in[2];
  const int*   edge_index = (const int*)  d_in[3];
  const float* W1 = (const float*)d_in[4];
  const float* B1 = (const float*)d_in[5];
  const float* W2 = (const float*)d_in[6];
  const float* B2 = (const float*)d_in[7];
  const float* W3 = (const float*)d_in[8];
  const float* B3 = (const float*)d_in[9];

  float* out      = (float*)d_out;
  float* node_out = out;                               // 50000*512 floats
  float* edge_out = out + (size_t)N_NODES * 512;       // 200000*512 floats (409.6 MB)

  // Scratch lives in the edge_out region: it is only written by k_edge at the
  // very end, after every scratch consumer has finished. Total use: ~68M floats
  // (272 MB) of the available 102.4M floats (409.6 MB). d_ws is untouched.
  float* scratch = edge_out;
  float* h       = scratch;                            // 0 .. 64.0M  (h[e][64])
  int*   counts  = (int*)(scratch + 64000000);
  int*   offsets = (int*)(scratch + 64100000);
  int*   cursor  = (int*)(scratch + 64200000);
  int*   order   = (int*)(scratch + 64300000);         // .. 65.3M

  k_zero_i<<<196, 256, 0, stream>>>(counts, N_NODES);

  k_hist<<<(N_ENV + 255) / 256, 256, 0, stream>>>(env_index, counts);

  k_scan<<<1, 64, 0, stream>>>(counts, offsets, cursor);

  k_scatter<<<(N_ENV + 255) / 256, 256, 0, stream>>>(env_index, cursor, order);

  k_mlp<<<(N_ENV + 255) / 256, 256, 0, stream>>>(
      env_vec, atom_attr, env_index, W1, B1, W2, B2, W3, B3, h);

  k_aggr_node<<<(N_NODES + 3) / 4, 256, 0, stream>>>(
      h, env_vec, offsets, counts, order, node_out);

  k_edge<<<N_EDGES / 2, 256, 0, stream>>>(node_out, edge_index, edge_out);
}

// Round 6
// 1354.825 us; speedup vs baseline: 1.4450x; 1.4450x over previous
//
#include <hip/hip_runtime.h>
#include <hip/hip_bf16.h>

#define N_NODES 50000
#define N_ENV   1000000
#define N_EDGES 200000

// tanh(x) = (e^{2x}-1)/(e^{2x}+1); clamp so exp never overflows
__device__ __forceinline__ float fast_tanh(float x){
  float xc = fminf(fmaxf(x, -10.f), 10.f);
  float t  = __expf(2.f * xc);
  return __fdividef(t - 1.f, t + 1.f);
}

__global__ void k_zero_i(int* __restrict__ p, int n){
  int i = blockIdx.x * blockDim.x + threadIdx.x;
  int stride = gridDim.x * blockDim.x;
  for (; i < n; i += stride) p[i] = 0;
}

// ---- CSR build: histogram by dst node ----
__global__ __launch_bounds__(256) void k_hist(
    const int* __restrict__ env_index, int* __restrict__ counts)
{
  int e = blockIdx.x * 256 + threadIdx.x;
  if (e >= N_ENV) return;
  atomicAdd(counts + env_index[N_ENV + e], 1);
}

// ---- single-wave exclusive scan over 50K counts (8 elems/lane/iter) ----
__global__ __launch_bounds__(64) void k_scan(
    const int* __restrict__ counts, int* __restrict__ offsets,
    int* __restrict__ cursor)
{
  int lane = threadIdx.x;
  int carry = 0;
  for (int base = 0; base < N_NODES; base += 512){
    int i0 = base + lane * 8;
    int c[8];
    #pragma unroll
    for (int j = 0; j < 8; j++){ int i = i0 + j; c[j] = (i < N_NODES) ? counts[i] : 0; }
    int local = 0;
    #pragma unroll
    for (int j = 0; j < 8; j++) local += c[j];
    int incl = local;
    #pragma unroll
    for (int off = 1; off < 64; off <<= 1){
      int t = __shfl_up(incl, off);
      if (lane >= off) incl += t;
    }
    int run = carry + incl - local;   // exclusive prefix for this lane's first elem
    #pragma unroll
    for (int j = 0; j < 8; j++){
      int i = i0 + j;
      if (i < N_NODES){ offsets[i] = run; cursor[i] = run; }
      run += c[j];
    }
    carry += __shfl(incl, 63);
  }
}

// ---- CSR build: scatter env ids into dst-grouped order ----
__global__ __launch_bounds__(256) void k_scatter(
    const int* __restrict__ env_index, int* __restrict__ cursor,
    int* __restrict__ order)
{
  int e = blockIdx.x * 256 + threadIdx.x;
  if (e >= N_ENV) return;
  int dst = env_index[N_ENV + e];
  int pos = atomicAdd(cursor + dst, 1);
  order[pos] = e;
}

// ---- MLP per env. Layer-3 outputs go through an LDS stage (no register
// array, no occupancy hit); flush emits full 64B lines, instruction-coalesced.
__global__ __launch_bounds__(256) void k_mlp(
    const float* __restrict__ env_vec, const float* __restrict__ atom_attr,
    const int*  __restrict__ env_index,
    const float* __restrict__ W1, const float* __restrict__ B1,
    const float* __restrict__ W2, const float* __restrict__ B2,
    const float* __restrict__ W3, const float* __restrict__ B3,
    float* __restrict__ h_out)
{
  // Transposed weights in LDS: contiguous along the reduction dim so the
  // wave-uniform inner-loop reads merge into broadcast ds_read_b128.
  __shared__ float sW1[32*9];    // sW1[j*9+i]  = W1[i*32+j]
  __shared__ float sW2[64*32];   // sW2[j*32+i] = W2[i*64+j]
  __shared__ float sW3[64*64];   // sW3[j*64+i] = W3[i*64+j]
  __shared__ float sB1[32], sB2[64], sB3[64];
  __shared__ float stage[256*17]; // [row][16 outs], pad 17: 2-way bank alias = free
  for (int k = threadIdx.x; k < 32*9;  k += 256){ int j = k/9,  i = k%9;  sW1[k] = W1[i*32+j]; }
  for (int k = threadIdx.x; k < 64*32; k += 256){ int j = k>>5, i = k&31; sW2[k] = W2[i*64+j]; }
  for (int k = threadIdx.x; k < 64*64; k += 256){ int j = k>>6, i = k&63; sW3[k] = W3[i*64+j]; }
  if (threadIdx.x < 32) sB1[threadIdx.x] = B1[threadIdx.x];
  if (threadIdx.x < 64) sB2[threadIdx.x] = B2[threadIdx.x];
  if (threadIdx.x < 64) sB3[threadIdx.x] = B3[threadIdx.x];
  __syncthreads();

  int e  = blockIdx.x * 256 + threadIdx.x;
  int el = min(e, N_ENV - 1);          // no early return (barriers below);
                                       // clamped loads, flush is row-guarded

  float v0 = env_vec[3*el+0];
  float v1 = env_vec[3*el+1];
  float v2 = env_vec[3*el+2];
  float r = sqrtf(v0*v0 + v1*v1 + v2*v2);
  float invr = 1.f / r;
  float xx = (r - 6.f) * (-1.f/3.f);                 // (r-RC)/(RS-RC)
  float mid = invr * (xx*xx*xx*(10.f + xx*(-15.f + 6.f*xx)) + 1.f);
  float snorm = (r < 3.f) ? invr : ((r < 6.f) ? mid : 0.f);

  int src = env_index[el];
  int dst = env_index[N_ENV + el];

  float x[9];
  x[0] = snorm;
  float4 sa = *reinterpret_cast<const float4*>(atom_attr + src*4);
  float4 da = *reinterpret_cast<const float4*>(atom_attr + dst*4);
  x[1]=sa.x; x[2]=sa.y; x[3]=sa.z; x[4]=sa.w;
  x[5]=da.x; x[6]=da.y; x[7]=da.z; x[8]=da.w;

  float h1[32];
  #pragma unroll
  for (int j = 0; j < 32; j++){
    float acc = sB1[j];
    #pragma unroll
    for (int i = 0; i < 9; i++) acc += x[i] * sW1[j*9 + i];
    h1[j] = fast_tanh(acc);
  }

  float h2[64];
  #pragma unroll
  for (int j = 0; j < 64; j++){
    float acc = sB2[j];
    #pragma unroll
    for (int i = 0; i < 32; i++) acc += h1[i] * sW2[j*32 + i];
    h2[j] = fast_tanh(acc);
  }

  // Layer 3: 4 chunks of 16 outputs. Each output goes straight to LDS
  // (no live register array -> VGPR stays ~round-1 level).
  const int tid = threadIdx.x;
  #pragma unroll
  for (int c = 0; c < 4; c++){
    #pragma unroll
    for (int dd = 0; dd < 16; dd++){
      int d = c*16 + dd;
      float acc = sB3[d];
      #pragma unroll
      for (int i = 0; i < 64; i++) acc += h2[i] * sW3[d*64 + i];
      stage[tid*17 + dd] = fast_tanh(acc) + h2[d];
    }
    __syncthreads();
    // Flush: 4 lanes per row emit one full 64B line per instruction.
    int rb = tid >> 2;            // 0..63
    int j  = tid & 3;             // 0..3
    #pragma unroll
    for (int p = 0; p < 4; p++){
      int rr = p*64 + rb;         // row within block
      float w0 = stage[rr*17 + j*4 + 0];
      float w1 = stage[rr*17 + j*4 + 1];
      float w2 = stage[rr*17 + j*4 + 2];
      float w3 = stage[rr*17 + j*4 + 3];
      int erow = blockIdx.x * 256 + rr;
      if (erow < N_ENV)
        *reinterpret_cast<float4*>(h_out + (size_t)erow*64 + c*16 + j*4) =
            make_float4(w0, w1, w2, w3);
    }
    __syncthreads();
  }
}

// ---- one WAVE per node: lane d owns h[e][d]; fused aggregate + self-outer ----
__global__ __launch_bounds__(256) void k_aggr_node(
    const float* __restrict__ h, const float* __restrict__ env_vec,
    const int* __restrict__ offsets, const int* __restrict__ counts,
    const int* __restrict__ order, float* __restrict__ node_out)
{
  int wid  = (blockIdx.x * 256 + threadIdx.x) >> 6;   // node id (wave-uniform)
  int lane = threadIdx.x & 63;
  if (wid >= N_NODES) return;
  int off = offsets[wid];
  int c   = counts[wid];

  float a0 = 0.f, a1 = 0.f, a2 = 0.f;
  int e = (c > 0) ? order[off] : 0;
  for (int k = 0; k < c; k++){
    // e is wave-uniform (same wid across the wave) — hoist to SGPR so the
    // env_vec broadcasts and order prefetch go down the scalar-mem pipe.
    int eu = __builtin_amdgcn_readfirstlane(e);
    int en = (k + 1 < c) ? order[off + k + 1] : eu;   // prefetch next env id
    float hv = h[(size_t)eu * 64 + lane];             // coalesced 256B wave read
    float v0 = env_vec[3*eu+0];                       // scalar broadcast loads
    float v1 = env_vec[3*eu+1];
    float v2 = env_vec[3*eu+2];
    a0 += hv * v0;
    a1 += hv * v1;
    a2 += hv * v2;
    e = en;
  }
  float inv = 1.f / fmaxf((float)c, 1.f);
  a0 *= inv; a1 *= inv; a2 *= inv;

  // desc[d][e2] = dot(aggr[d], aggr[e2]), e2 < 8 — fetch aggr[e2] via shuffle
  float o[8];
  #pragma unroll
  for (int e2 = 0; e2 < 8; e2++){
    float b0 = __shfl(a0, e2);
    float b1 = __shfl(a1, e2);
    float b2 = __shfl(a2, e2);
    o[e2] = a0*b0 + a1*b1 + a2*b2;
  }
  float* dst = node_out + (size_t)wid * 512 + lane * 8;
  *reinterpret_cast<float4*>(dst)     = make_float4(o[0], o[1], o[2], o[3]);
  *reinterpret_cast<float4*>(dst + 4) = make_float4(o[4], o[5], o[6], o[7]);
}

// 2 edges per 256-thread block; 128 threads per edge, one float4 (16B) per thread
__global__ __launch_bounds__(256) void k_edge(
    const float* __restrict__ node_out, const int* __restrict__ edge_index,
    float* __restrict__ edge_out)
{
  int t = threadIdx.x;
  int e = blockIdx.x * 2 + (t >> 7);
  int l = t & 127;
  int s  = edge_index[e];
  int dn = edge_index[N_EDGES + e];
  const float4* rs = reinterpret_cast<const float4*>(node_out + (size_t)s  * 512);
  const float4* rd = reinterpret_cast<const float4*>(node_out + (size_t)dn * 512);
  float4 a = rs[l];
  float4 b = rd[l];
  float4 o = make_float4(a.x + b.x, a.y + b.y, a.z + b.z, a.w + b.w);
  reinterpret_cast<float4*>(edge_out + (size_t)e * 512)[l] = o;
}

extern "C" void kernel_launch(void* const* d_in, const int* in_sizes, int n_in,
                              void* d_out, int out_size, void* d_ws, size_t ws_size,
                              hipStream_t stream) {
  const float* env_vec    = (const float*)d_in[0];
  const float* atom_attr  = (const float*)d_in[1];
  const int*   env_index  = (const int*)  d_in[2];
  const int*   edge_index = (const int*)  d_in[3];
  const float* W1 = (const float*)d_in[4];
  const float* B1 = (const float*)d_in[5];
  const float* W2 = (const float*)d_in[6];
  const float* B2 = (const float*)d_in[7];
  const float* W3 = (const float*)d_in[8];
  const float* B3 = (const float*)d_in[9];

  float* out      = (float*)d_out;
  float* node_out = out;                               // 50000*512 floats
  float* edge_out = out + (size_t)N_NODES * 512;       // 200000*512 floats (409.6 MB)

  // Scratch lives in the edge_out region: it is only written by k_edge at the
  // very end, after every scratch consumer has finished. Total use: ~68M floats
  // (272 MB) of the available 102.4M floats (409.6 MB). d_ws is untouched.
  float* scratch = edge_out;
  float* h       = scratch;                            // 0 .. 64.0M  (h[e][64])
  int*   counts  = (int*)(scratch + 64000000);
  int*   offsets = (int*)(scratch + 64100000);
  int*   cursor  = (int*)(scratch + 64200000);
  int*   order   = (int*)(scratch + 64300000);         // .. 65.3M

  k_zero_i<<<196, 256, 0, stream>>>(counts, N_NODES);

  k_hist<<<(N_ENV + 255) / 256, 256, 0, stream>>>(env_index, counts);

  k_scan<<<1, 64, 0, stream>>>(counts, offsets, cursor);

  k_scatter<<<(N_ENV + 255) / 256, 256, 0, stream>>>(env_index, cursor, order);

  k_mlp<<<(N_ENV + 255) / 256, 256, 0, stream>>>(
      env_vec, atom_attr, env_index, W1, B1, W2, B2, W3, B3, h);

  k_aggr_node<<<(N_NODES + 3) / 4, 256, 0, stream>>>(
      h, env_vec, offsets, counts, order, node_out);

  k_edge<<<N_EDGES / 2, 256, 0, stream>>>(node_out, edge_index, edge_out);
}

// Round 7
// 1264.687 us; speedup vs baseline: 1.5480x; 1.0713x over previous
//
#include <hip/hip_runtime.h>
#include <hip/hip_bf16.h>

#define N_NODES 50000
#define N_ENV   1000000
#define N_EDGES 200000

// tanh(x) = (e^{2x}-1)/(e^{2x}+1); clamp so exp never overflows
__device__ __forceinline__ float fast_tanh(float x){
  float xc = fminf(fmaxf(x, -10.f), 10.f);
  float t  = __expf(2.f * xc);
  return __fdividef(t - 1.f, t + 1.f);
}

__global__ void k_zero_i(int* __restrict__ p, int n){
  int i = blockIdx.x * blockDim.x + threadIdx.x;
  int stride = gridDim.x * blockDim.x;
  for (; i < n; i += stride) p[i] = 0;
}

// ---- CSR build: histogram by dst node ----
__global__ __launch_bounds__(256) void k_hist(
    const int* __restrict__ env_index, int* __restrict__ counts)
{
  int e = blockIdx.x * 256 + threadIdx.x;
  if (e >= N_ENV) return;
  atomicAdd(counts + env_index[N_ENV + e], 1);
}

// ---- single-BLOCK (1024-thread, 16-wave) exclusive scan over 50K counts.
// Two-level: wave shuffle-scan + cross-wave LDS scan. 7 chunk iterations.
// (Previous 1-wave version was a serial single-CU latency chain.)
__global__ __launch_bounds__(1024) void k_scan(
    const int* __restrict__ counts, int* __restrict__ offsets,
    int* __restrict__ cursor)
{
  __shared__ int wsum[16];
  __shared__ int s_carry, s_tot;
  int tid = threadIdx.x, lane = tid & 63, w = tid >> 6;
  if (tid == 0) s_carry = 0;
  __syncthreads();
  for (int base = 0; base < N_NODES; base += 8192){
    int i0 = base + tid * 8;
    int c[8];
    #pragma unroll
    for (int j = 0; j < 8; j++){ int i = i0 + j; c[j] = (i < N_NODES) ? counts[i] : 0; }
    int local = 0;
    #pragma unroll
    for (int j = 0; j < 8; j++) local += c[j];
    int incl = local;
    #pragma unroll
    for (int off = 1; off < 64; off <<= 1){
      int t = __shfl_up(incl, off);
      if (lane >= off) incl += t;
    }
    if (lane == 63) wsum[w] = incl;
    __syncthreads();
    if (w == 0 && lane < 16){
      int v = wsum[lane];
      int winc = v;
      #pragma unroll
      for (int off = 1; off < 16; off <<= 1){
        int t = __shfl_up(winc, off);
        if (lane >= off) winc += t;
      }
      wsum[lane] = winc - v;            // exclusive wave prefix
      if (lane == 15) s_tot = winc;     // chunk total
    }
    __syncthreads();
    int run = s_carry + wsum[w] + incl - local;  // exclusive prefix of first elem
    #pragma unroll
    for (int j = 0; j < 8; j++){
      int i = i0 + j;
      if (i < N_NODES){ offsets[i] = run; cursor[i] = run; }
      run += c[j];
    }
    __syncthreads();                    // all uses of s_carry done
    if (tid == 0) s_carry += s_tot;
    __syncthreads();
  }
}

// ---- CSR build: scatter env ids into dst-grouped order ----
__global__ __launch_bounds__(256) void k_scatter(
    const int* __restrict__ env_index, int* __restrict__ cursor,
    int* __restrict__ order)
{
  int e = blockIdx.x * 256 + threadIdx.x;
  if (e >= N_ENV) return;
  int dst = env_index[N_ENV + e];
  int pos = atomicAdd(cursor + dst, 1);
  order[pos] = e;
}

// ---- MLP, 2 envs per thread. k_mlp is LDS-instruction-bound (broadcast
// weight reads ~27/env at ~12cyc on the shared per-CU LDS pipe = ~500µs/CU);
// sharing each weight read across TWO envs' FMAs halves LDS instr/env.
// Layer-3 still stages through LDS (512 rows) for full-line global writes.
__global__ __launch_bounds__(256) void k_mlp(
    const float* __restrict__ env_vec, const float* __restrict__ atom_attr,
    const int*  __restrict__ env_index,
    const float* __restrict__ W1, const float* __restrict__ B1,
    const float* __restrict__ W2, const float* __restrict__ B2,
    const float* __restrict__ W3, const float* __restrict__ B3,
    float* __restrict__ h_out)
{
  // Transposed weights in LDS: contiguous along the reduction dim so the
  // wave-uniform inner-loop reads merge into broadcast ds_read_b128.
  __shared__ float sW1[32*9];    // sW1[j*9+i]  = W1[i*32+j]
  __shared__ float sW2[64*32];   // sW2[j*32+i] = W2[i*64+j]
  __shared__ float sW3[64*64];   // sW3[j*64+i] = W3[i*64+j]
  __shared__ float sB1[32], sB2[64], sB3[64];
  __shared__ float stage[512*17]; // [row][16 outs], pad 17: 2-way bank alias = free
  for (int k = threadIdx.x; k < 32*9;  k += 256){ int j = k/9,  i = k%9;  sW1[k] = W1[i*32+j]; }
  for (int k = threadIdx.x; k < 64*32; k += 256){ int j = k>>5, i = k&31; sW2[k] = W2[i*64+j]; }
  for (int k = threadIdx.x; k < 64*64; k += 256){ int j = k>>6, i = k&63; sW3[k] = W3[i*64+j]; }
  if (threadIdx.x < 32) sB1[threadIdx.x] = B1[threadIdx.x];
  if (threadIdx.x < 64) sB2[threadIdx.x] = B2[threadIdx.x];
  if (threadIdx.x < 64) sB3[threadIdx.x] = B3[threadIdx.x];
  __syncthreads();

  const int tid  = threadIdx.x;
  const int base = blockIdx.x * 512;
  int eA = base + tid;
  int eB = eA + 256;
  int elA = min(eA, N_ENV - 1);        // no early return (barriers below);
  int elB = min(eB, N_ENV - 1);        // clamped loads, flush is row-guarded

  float xA[9], xB[9];
  {
    float v0 = env_vec[3*elA+0], v1 = env_vec[3*elA+1], v2 = env_vec[3*elA+2];
    float r = sqrtf(v0*v0 + v1*v1 + v2*v2);
    float invr = 1.f / r;
    float xx = (r - 6.f) * (-1.f/3.f);
    float mid = invr * (xx*xx*xx*(10.f + xx*(-15.f + 6.f*xx)) + 1.f);
    xA[0] = (r < 3.f) ? invr : ((r < 6.f) ? mid : 0.f);
    int src = env_index[elA], dst = env_index[N_ENV + elA];
    float4 sa = *reinterpret_cast<const float4*>(atom_attr + src*4);
    float4 da = *reinterpret_cast<const float4*>(atom_attr + dst*4);
    xA[1]=sa.x; xA[2]=sa.y; xA[3]=sa.z; xA[4]=sa.w;
    xA[5]=da.x; xA[6]=da.y; xA[7]=da.z; xA[8]=da.w;
  }
  {
    float v0 = env_vec[3*elB+0], v1 = env_vec[3*elB+1], v2 = env_vec[3*elB+2];
    float r = sqrtf(v0*v0 + v1*v1 + v2*v2);
    float invr = 1.f / r;
    float xx = (r - 6.f) * (-1.f/3.f);
    float mid = invr * (xx*xx*xx*(10.f + xx*(-15.f + 6.f*xx)) + 1.f);
    xB[0] = (r < 3.f) ? invr : ((r < 6.f) ? mid : 0.f);
    int src = env_index[elB], dst = env_index[N_ENV + elB];
    float4 sa = *reinterpret_cast<const float4*>(atom_attr + src*4);
    float4 da = *reinterpret_cast<const float4*>(atom_attr + dst*4);
    xB[1]=sa.x; xB[2]=sa.y; xB[3]=sa.z; xB[4]=sa.w;
    xB[5]=da.x; xB[6]=da.y; xB[7]=da.z; xB[8]=da.w;
  }

  float h1A[32], h1B[32];
  #pragma unroll
  for (int j = 0; j < 32; j++){
    float accA = sB1[j], accB = sB1[j];
    #pragma unroll
    for (int i = 0; i < 9; i++){ float w = sW1[j*9 + i]; accA += xA[i]*w; accB += xB[i]*w; }
    h1A[j] = fast_tanh(accA);
    h1B[j] = fast_tanh(accB);
  }

  float h2A[64], h2B[64];
  #pragma unroll
  for (int j = 0; j < 64; j++){
    float accA = sB2[j], accB = sB2[j];
    #pragma unroll
    for (int i = 0; i < 32; i++){ float w = sW2[j*32 + i]; accA += h1A[i]*w; accB += h1B[i]*w; }
    h2A[j] = fast_tanh(accA);
    h2B[j] = fast_tanh(accB);
  }

  // Layer 3: 4 chunks of 16 outputs, both envs per weight read.
  #pragma unroll
  for (int c = 0; c < 4; c++){
    #pragma unroll
    for (int dd = 0; dd < 16; dd++){
      int d = c*16 + dd;
      float accA = sB3[d], accB = sB3[d];
      #pragma unroll
      for (int i = 0; i < 64; i++){ float w = sW3[d*64 + i]; accA += h2A[i]*w; accB += h2B[i]*w; }
      stage[tid*17 + dd]       = fast_tanh(accA) + h2A[d];
      stage[(tid+256)*17 + dd] = fast_tanh(accB) + h2B[d];
    }
    __syncthreads();
    // Flush 512 rows: 4 lanes per row emit one full 64B line per float4.
    int rb = tid >> 2;            // 0..63
    int j  = tid & 3;             // 0..3
    #pragma unroll
    for (int p = 0; p < 8; p++){
      int rr = p*64 + rb;         // row within block (0..511)
      float w0 = stage[rr*17 + j*4 + 0];
      float w1 = stage[rr*17 + j*4 + 1];
      float w2 = stage[rr*17 + j*4 + 2];
      float w3 = stage[rr*17 + j*4 + 3];
      int erow = base + rr;
      if (erow < N_ENV)
        *reinterpret_cast<float4*>(h_out + (size_t)erow*64 + c*16 + j*4) =
            make_float4(w0, w1, w2, w3);
    }
    __syncthreads();
  }
}

// ---- one WAVE per node: lane d owns h[e][d]; fused aggregate + self-outer ----
__global__ __launch_bounds__(256) void k_aggr_node(
    const float* __restrict__ h, const float* __restrict__ env_vec,
    const int* __restrict__ offsets, const int* __restrict__ counts,
    const int* __restrict__ order, float* __restrict__ node_out)
{
  int wid  = (blockIdx.x * 256 + threadIdx.x) >> 6;   // node id (wave-uniform)
  int lane = threadIdx.x & 63;
  if (wid >= N_NODES) return;
  int off = offsets[wid];
  int c   = counts[wid];

  float a0 = 0.f, a1 = 0.f, a2 = 0.f;
  if (c > 0){
    // e is wave-uniform — readfirstlane pushes env_vec/order traffic to the
    // scalar pipe. h row for iter k+1 is prefetched during iter k's FMAs.
    int e = __builtin_amdgcn_readfirstlane(order[off]);
    float hv = h[(size_t)e * 64 + lane];              // coalesced 256B wave read
    for (int k = 0; k < c; k++){
      int en = (k + 1 < c) ? __builtin_amdgcn_readfirstlane(order[off + k + 1]) : e;
      float hv_n = h[(size_t)en * 64 + lane];         // prefetch next row
      float v0 = env_vec[3*e+0];                      // scalar broadcast loads
      float v1 = env_vec[3*e+1];
      float v2 = env_vec[3*e+2];
      a0 += hv * v0;
      a1 += hv * v1;
      a2 += hv * v2;
      e = en; hv = hv_n;
    }
  }
  float inv = 1.f / fmaxf((float)c, 1.f);
  a0 *= inv; a1 *= inv; a2 *= inv;

  // desc[d][e2] = dot(aggr[d], aggr[e2]), e2 < 8 — fetch aggr[e2] via shuffle
  float o[8];
  #pragma unroll
  for (int e2 = 0; e2 < 8; e2++){
    float b0 = __shfl(a0, e2);
    float b1 = __shfl(a1, e2);
    float b2 = __shfl(a2, e2);
    o[e2] = a0*b0 + a1*b1 + a2*b2;
  }
  float* dst = node_out + (size_t)wid * 512 + lane * 8;
  *reinterpret_cast<float4*>(dst)     = make_float4(o[0], o[1], o[2], o[3]);
  *reinterpret_cast<float4*>(dst + 4) = make_float4(o[4], o[5], o[6], o[7]);
}

// 2 edges per 256-thread block; 128 threads per edge, one float4 (16B) per thread
__global__ __launch_bounds__(256) void k_edge(
    const float* __restrict__ node_out, const int* __restrict__ edge_index,
    float* __restrict__ edge_out)
{
  int t = threadIdx.x;
  int e = blockIdx.x * 2 + (t >> 7);
  int l = t & 127;
  int s  = edge_index[e];
  int dn = edge_index[N_EDGES + e];
  const float4* rs = reinterpret_cast<const float4*>(node_out + (size_t)s  * 512);
  const float4* rd = reinterpret_cast<const float4*>(node_out + (size_t)dn * 512);
  float4 a = rs[l];
  float4 b = rd[l];
  float4 o = make_float4(a.x + b.x, a.y + b.y, a.z + b.z, a.w + b.w);
  reinterpret_cast<float4*>(edge_out + (size_t)e * 512)[l] = o;
}

extern "C" void kernel_launch(void* const* d_in, const int* in_sizes, int n_in,
                              void* d_out, int out_size, void* d_ws, size_t ws_size,
                              hipStream_t stream) {
  const float* env_vec    = (const float*)d_in[0];
  const float* atom_attr  = (const float*)d_in[1];
  const int*   env_index  = (const int*)  d_in[2];
  const int*   edge_index = (const int*)  d_in[3];
  const float* W1 = (const float*)d_in[4];
  const float* B1 = (const float*)d_in[5];
  const float* W2 = (const float*)d_in[6];
  const float* B2 = (const float*)d_in[7];
  const float* W3 = (const float*)d_in[8];
  const float* B3 = (const float*)d_in[9];

  float* out      = (float*)d_out;
  float* node_out = out;                               // 50000*512 floats
  float* edge_out = out + (size_t)N_NODES * 512;       // 200000*512 floats (409.6 MB)

  // Scratch lives in the edge_out region: it is only written by k_edge at the
  // very end, after every scratch consumer has finished. Total use: ~68M floats
  // (272 MB) of the available 102.4M floats (409.6 MB). d_ws is untouched.
  float* scratch = edge_out;
  float* h       = scratch;                            // 0 .. 64.0M  (h[e][64])
  int*   counts  = (int*)(scratch + 64000000);
  int*   offsets = (int*)(scratch + 64100000);
  int*   cursor  = (int*)(scratch + 64200000);
  int*   order   = (int*)(scratch + 64300000);         // .. 65.3M

  k_zero_i<<<196, 256, 0, stream>>>(counts, N_NODES);

  k_hist<<<(N_ENV + 255) / 256, 256, 0, stream>>>(env_index, counts);

  k_scan<<<1, 1024, 0, stream>>>(counts, offsets, cursor);

  k_scatter<<<(N_ENV + 255) / 256, 256, 0, stream>>>(env_index, cursor, order);

  k_mlp<<<(N_ENV + 511) / 512, 256, 0, stream>>>(
      env_vec, atom_attr, env_index, W1, B1, W2, B2, W3, B3, h);

  k_aggr_node<<<(N_NODES + 3) / 4, 256, 0, stream>>>(
      h, env_vec, offsets, counts, order, node_out);

  k_edge<<<N_EDGES / 2, 256, 0, stream>>>(node_out, edge_index, edge_out);
}